// Round 1
// baseline (710.143 us; speedup 1.0000x reference)
//
#include <hip/hip_runtime.h>
#include <stdint.h>

#define N_NODES 100000
#define N_EDGES 800000

typedef unsigned short u16;
typedef __attribute__((ext_vector_type(8))) short bf16x8;
typedef __attribute__((ext_vector_type(4))) float f32x4;

struct alignas(8) U16x4 { u16 x, y, z, w; };

__device__ __forceinline__ u16 f2b(float f) {
    union { float f; unsigned u; } x; x.f = f;
    unsigned r = (x.u + 0x7FFFu + ((x.u >> 16) & 1u)) >> 16;
    return (u16)r;
}
__device__ __forceinline__ float b2f(u16 h) {
    union { unsigned u; float f; } x; x.u = ((unsigned)h) << 16;
    return x.f;
}

__device__ __forceinline__ void gload_lds16(const void* g, void* l) {
    __builtin_amdgcn_global_load_lds(
        (const __attribute__((address_space(1))) char*)(uintptr_t)g,
        (__attribute__((address_space(3))) char*)(uintptr_t)l,
        16, 0, 0);
}

// ---------------- casts & weight packing ----------------

__global__ void k_cast_bf16(const float* __restrict__ in, u16* __restrict__ out, int n4) {
    int i = blockIdx.x * blockDim.x + threadIdx.x;
    if (i < n4) {
        float4 v = ((const float4*)in)[i];
        U16x4 o; o.x = f2b(v.x); o.y = f2b(v.y); o.z = f2b(v.z); o.w = f2b(v.w);
        ((U16x4*)out)[i] = o;
    }
}

// dst[n*Ktot + k] = bf16( k<K0 ? s0[k*Ncol+n] : s1[(k-K0)*Ncol+n] )   (transposed pack)
__global__ void k_pack_wt(const float* __restrict__ s0, int K0,
                          const float* __restrict__ s1, int K1,
                          int Ncol, u16* __restrict__ dst) {
    int idx = blockIdx.x * blockDim.x + threadIdx.x;
    int Ktot = K0 + K1;
    if (idx < Ncol * Ktot) {
        int n = idx / Ktot, k = idx - n * Ktot;
        float v = (k < K0) ? s0[(size_t)k * Ncol + n] : s1[(size_t)(k - K0) * Ncol + n];
        dst[idx] = f2b(v);
    }
}

// ---------------- CSR build ----------------

__global__ void k_count(const int* __restrict__ dst, int* __restrict__ deg) {
    int e = blockIdx.x * blockDim.x + threadIdx.x;
    if (e < N_EDGES) atomicAdd(&deg[dst[e]], 1);
}

__global__ void k_scan1(const int* __restrict__ deg, int* __restrict__ excl,
                        int* __restrict__ bsum, int n) {
    __shared__ int sh[512];
    int t = threadIdx.x;
    int base = blockIdx.x * 2048 + t * 4;
    int v0 = (base + 0 < n) ? deg[base + 0] : 0;
    int v1 = (base + 1 < n) ? deg[base + 1] : 0;
    int v2 = (base + 2 < n) ? deg[base + 2] : 0;
    int v3 = (base + 3 < n) ? deg[base + 3] : 0;
    int tot = v0 + v1 + v2 + v3;
    sh[t] = tot;
    __syncthreads();
    for (int off = 1; off < 512; off <<= 1) {
        int x = (t >= off) ? sh[t - off] : 0;
        __syncthreads();
        sh[t] += x;
        __syncthreads();
    }
    int run = sh[t] - tot;
    if (base + 0 < n) excl[base + 0] = run; run += v0;
    if (base + 1 < n) excl[base + 1] = run; run += v1;
    if (base + 2 < n) excl[base + 2] = run; run += v2;
    if (base + 3 < n) excl[base + 3] = run;
    if (t == 511) bsum[blockIdx.x] = sh[t];
}

__global__ void k_scan2(int* __restrict__ bsum, int nb) {
    __shared__ int sh[64];
    int t = threadIdx.x;
    int v = (t < nb) ? bsum[t] : 0;
    sh[t] = v;
    __syncthreads();
    for (int off = 1; off < 64; off <<= 1) {
        int x = (t >= off) ? sh[t - off] : 0;
        __syncthreads();
        sh[t] += x;
        __syncthreads();
    }
    if (t < nb) bsum[t] = sh[t] - v;
}

__global__ void k_scan3(int* __restrict__ excl, const int* __restrict__ bsum,
                        int* __restrict__ cursor, int n) {
    int i = blockIdx.x * blockDim.x + threadIdx.x;
    if (i < n) {
        int v = excl[i] + bsum[i >> 11];
        excl[i] = v;
        cursor[i] = v;
    }
}

__global__ void k_scatter(const int* __restrict__ src, const int* __restrict__ dst,
                          int* __restrict__ cursor, int* __restrict__ esrc) {
    int e = blockIdx.x * blockDim.x + threadIdx.x;
    if (e < N_EDGES) {
        int p = atomicAdd(&cursor[dst[e]], 1);
        esrc[p] = src[e];
    }
}

// ---------------- segment-max aggregation (one wave per node) ----------------
// y = [conf(64) | x(192)] read from split bf16 buffers; out agg[N,256] bf16.

__global__ __launch_bounds__(256) void k_agg(
    const u16* __restrict__ conf16, const u16* __restrict__ x16,
    const int* __restrict__ indptr, const int* __restrict__ deg,
    const int* __restrict__ esrc, u16* __restrict__ agg) {
    int node = blockIdx.x * 4 + (threadIdx.x >> 6);
    if (node >= N_NODES) return;
    int lane = threadIdx.x & 63;
    int start = indptr[node];
    int d = deg[node];
    float m0 = -1e30f, m1 = -1e30f, m2 = -1e30f, m3 = -1e30f;
    const bool isConf = lane < 16;
    const int off = isConf ? lane * 4 : lane * 4 - 64;
    const u16* basep = isConf ? conf16 : x16;
    const int stride = isConf ? 64 : 192;
    for (int e = 0; e < d; ++e) {
        int s = esrc[start + e];
        U16x4 v = *(const U16x4*)(basep + (size_t)s * stride + off);
        m0 = fmaxf(m0, b2f(v.x));
        m1 = fmaxf(m1, b2f(v.y));
        m2 = fmaxf(m2, b2f(v.z));
        m3 = fmaxf(m3, b2f(v.w));
    }
    if (d == 0) { m0 = m1 = m2 = m3 = 0.f; }
    U16x4 o; o.x = f2b(m0); o.y = f2b(m1); o.z = f2b(m2); o.w = f2b(m3);
    *(U16x4*)(agg + (size_t)node * 256 + lane * 4) = o;
}

// ---------------- MFMA GEMM ----------------
// C[nrows, BN] = concat_K(A0|A1|A2) @ Bt^T (+bias, +epilogue)
// Bt is prepacked transposed: [BN][Ktot] bf16.
// BM=128 rows/block, full BN width per block (grid.x = row blocks only)
// 8 waves as 2(row)x4(col); wave tile 64 x (BN/4); 16x16x32 bf16 MFMA.
// EPI: 0 = bias -> bf16 out        (sage linear)
//      1 = bias,lrelu -> bf16 out  (mlp hidden)
//      2 = bias,lrelu -> f32 + bf16 out (prenet final)
//      3 = resid + lrelu(bias+acc) -> f32 + bf16 out (mlp final + residual)

template<int BN, int EPI>
__global__ __launch_bounds__(512, 2) void k_gemm(
    const u16* __restrict__ A0, int K0,
    const u16* __restrict__ A1, int K1,
    const u16* __restrict__ A2, int K2,
    const u16* __restrict__ Bt,
    const float* __restrict__ bias,
    float* __restrict__ outf,
    u16* __restrict__ outb,
    const float* __restrict__ resid,
    int nrows)
{
    constexpr int FN = BN / 64;           // frags per wave in N (4 or 3)
    constexpr int ASZ = 128 * 32;         // A tile elems
    constexpr int BSZ = BN * 32;          // B tile elems
    constexpr int BSLOTS = BN * 4;        // 16B slots in B tile
    __shared__ u16 lds[2][ASZ + BSZ] __attribute__((aligned(16)));

    const int tid = threadIdx.x;
    const int wave = tid >> 6;
    const int lane = tid & 63;
    const int wr = wave >> 2;             // 0..1
    const int wc = wave & 3;              // 0..3
    const int rowbase = blockIdx.x * 128;
    const int Ktot = K0 + K1 + K2;
    const int nk = Ktot >> 5;

    f32x4 zero = {0.f, 0.f, 0.f, 0.f};
    f32x4 acc[4][FN];
    #pragma unroll
    for (int fm = 0; fm < 4; ++fm)
        #pragma unroll
        for (int fn = 0; fn < FN; ++fn)
            acc[fm][fn] = zero;

    auto stage = [&](int buf, int k0) {
        const u16* segp; int segoff, segK;
        if (k0 < K0)           { segp = A0; segoff = k0;           segK = K0; }
        else if (k0 < K0 + K1) { segp = A1; segoff = k0 - K0;      segK = K1; }
        else                   { segp = A2; segoff = k0 - K0 - K1; segK = K2; }
        {   // A tile [128][32]: slot=tid -> row=tid>>2, k8=(tid&3)*8
            int grow = rowbase + (tid >> 2);
            if (grow >= nrows) grow = nrows - 1;
            const u16* g = segp + (size_t)grow * segK + segoff + (tid & 3) * 8;
            u16* l = &lds[buf][wave * 512];
            gload_lds16(g, l);
        }
        #pragma unroll
        for (int it = 0; it < (BSLOTS + 511) / 512; ++it) {
            int slot = it * 512 + tid;
            if (slot < BSLOTS) {          // wave-uniform predicate
                int nn = slot >> 2;       // col
                const u16* g = Bt + (size_t)nn * Ktot + k0 + (slot & 3) * 8;
                u16* l = &lds[buf][ASZ + it * 4096 + wave * 512];
                gload_lds16(g, l);
            }
        }
    };

    stage(0, 0);
    __syncthreads();

    const int l15 = lane & 15, l4 = lane >> 4;

    for (int ks = 0; ks < nk; ++ks) {
        const int cur = ks & 1;
        if (ks + 1 < nk) stage(cur ^ 1, (ks + 1) * 32);
        const u16* la = &lds[cur][0];
        const u16* lb = &lds[cur][ASZ];
        bf16x8 a[4], b[FN];
        #pragma unroll
        for (int fm = 0; fm < 4; ++fm)
            a[fm] = *(const bf16x8*)(la + (wr * 64 + fm * 16 + l15) * 32 + l4 * 8);
        #pragma unroll
        for (int fn = 0; fn < FN; ++fn)
            b[fn] = *(const bf16x8*)(lb + (wc * (FN * 16) + fn * 16 + l15) * 32 + l4 * 8);
        #pragma unroll
        for (int fm = 0; fm < 4; ++fm)
            #pragma unroll
            for (int fn = 0; fn < FN; ++fn)
                acc[fm][fn] = __builtin_amdgcn_mfma_f32_16x16x32_bf16(a[fm], b[fn], acc[fm][fn], 0, 0, 0);
        __syncthreads();
    }

    // epilogue: C/D layout col = lane&15, row = (lane>>4)*4 + r
    const int r0 = rowbase + wr * 64;
    const int c0 = wc * (FN * 16);
    #pragma unroll
    for (int fn = 0; fn < FN; ++fn) {
        const int col = c0 + fn * 16 + l15;
        const float bs = bias[col];
        #pragma unroll
        for (int fm = 0; fm < 4; ++fm) {
            #pragma unroll
            for (int r = 0; r < 4; ++r) {
                const int row = r0 + fm * 16 + l4 * 4 + r;
                if (row < nrows) {
                    float v = acc[fm][fn][r] + bs;
                    if (EPI >= 1) v = (v >= 0.f) ? v : 0.2f * v;
                    if (EPI == 3) v += resid[(size_t)row * BN + col];
                    if (EPI <= 1) {
                        outb[(size_t)row * BN + col] = f2b(v);
                    } else {
                        outf[(size_t)row * BN + col] = v;
                        outb[(size_t)row * BN + col] = f2b(v);
                    }
                }
            }
        }
    }
}

// ---------------- host ----------------

extern "C" void kernel_launch(void* const* d_in, const int* in_sizes, int n_in,
                              void* d_out, int out_size, void* d_ws, size_t ws_size,
                              hipStream_t stream)
{
    (void)in_sizes; (void)n_in; (void)out_size; (void)ws_size;
    const float* node = (const float*)d_in[0];
    const float* conf = (const float*)d_in[1];
    const int* edges  = (const int*)d_in[2];
    const float* pw0  = (const float*)d_in[3];
    const float* pb0  = (const float*)d_in[4];
    const float* pw1  = (const float*)d_in[5];
    const float* pb1  = (const float*)d_in[6];
    const float* W[14];
    for (int i = 0; i < 14; ++i) W[i] = (const float*)d_in[7 + i];
    // per layer l: W[7l+0]=wl, +1=bl, +2=wr, +3=mw0, +4=mb0, +5=mw1, +6=mb1
    float* out = (float*)d_out;
    const int* e_src = edges;
    const int* e_dst = edges + N_EDGES;

    char* w = (char*)d_ws;
    auto alloc = [&](size_t b) { char* p = w; w += (b + 255) & ~(size_t)255; return p; };
    u16* conf16 = (u16*)alloc((size_t)N_NODES * 64 * 2);
    u16* node16 = (u16*)alloc((size_t)N_NODES * 192 * 2);   // prenet input, later h
    u16* x16    = (u16*)alloc((size_t)N_NODES * 192 * 2);   // bf16 copy of residual stream
    u16* agg16  = (u16*)alloc((size_t)N_NODES * 256 * 2);   // agg, then s (in-place)
    int* deg    = (int*)alloc((size_t)N_NODES * 4);
    int* indptr = (int*)alloc((size_t)N_NODES * 4);
    int* cursor = (int*)alloc((size_t)N_NODES * 4);
    int* esrc   = (int*)alloc((size_t)N_EDGES * 4);
    int* bsum   = (int*)alloc(4096);
    u16* pw0t   = (u16*)alloc((size_t)192 * 256 * 2);
    u16* pw1t   = (u16*)alloc((size_t)192 * 192 * 2);
    u16 *sB[2], *mw0t[2], *mw1t[2];
    for (int l = 0; l < 2; ++l) {
        sB[l]   = (u16*)alloc((size_t)256 * 512 * 2);
        mw0t[l] = (u16*)alloc((size_t)192 * 256 * 2);
        mw1t[l] = (u16*)alloc((size_t)192 * 192 * 2);
    }

    // input casts
    k_cast_bf16<<<(N_NODES * 64 / 4 + 255) / 256, 256, 0, stream>>>(conf, conf16, N_NODES * 64 / 4);
    k_cast_bf16<<<(N_NODES * 192 / 4 + 255) / 256, 256, 0, stream>>>(node, node16, N_NODES * 192 / 4);
    // weight packs (transposed bf16)
    k_pack_wt<<<(192 * 256 + 255) / 256, 256, 0, stream>>>(pw0, 256, nullptr, 0, 192, pw0t);
    k_pack_wt<<<(192 * 192 + 255) / 256, 256, 0, stream>>>(pw1, 192, nullptr, 0, 192, pw1t);
    for (int l = 0; l < 2; ++l) {
        k_pack_wt<<<(256 * 512 + 255) / 256, 256, 0, stream>>>(W[7*l+0], 256, W[7*l+2], 256, 256, sB[l]);
        k_pack_wt<<<(192 * 256 + 255) / 256, 256, 0, stream>>>(W[7*l+3], 256, nullptr, 0, 192, mw0t[l]);
        k_pack_wt<<<(192 * 192 + 255) / 256, 256, 0, stream>>>(W[7*l+5], 192, nullptr, 0, 192, mw1t[l]);
    }
    // CSR (edges constant -> build once per launch)
    (void)hipMemsetAsync(deg, 0, (size_t)N_NODES * 4, stream);
    k_count<<<(N_EDGES + 255) / 256, 256, 0, stream>>>(e_dst, deg);
    int nb = (N_NODES + 2047) / 2048;
    k_scan1<<<nb, 512, 0, stream>>>(deg, indptr, bsum, N_NODES);
    k_scan2<<<1, 64, 0, stream>>>(bsum, nb);
    k_scan3<<<(N_NODES + 255) / 256, 256, 0, stream>>>(indptr, bsum, cursor, N_NODES);
    k_scatter<<<(N_EDGES + 255) / 256, 256, 0, stream>>>(e_src, e_dst, cursor, esrc);

    const int gblk = (N_NODES + 127) / 128;   // 782
    // prenet: t0 = lrelu([conf|node]@w0 + b0) -> x16 ; x = lrelu(t0@w1 + b1) -> out(f32) + x16
    k_gemm<192, 1><<<gblk, 512, 0, stream>>>(conf16, 64, node16, 192, nullptr, 0,
                                             pw0t, pb0, nullptr, x16, nullptr, N_NODES);
    k_gemm<192, 2><<<gblk, 512, 0, stream>>>(x16, 192, nullptr, 0, nullptr, 0,
                                             pw1t, pb1, out, x16, nullptr, N_NODES);
    for (int l = 0; l < 2; ++l) {
        // agg = segmax over in-neighbors of [conf|x]
        k_agg<<<N_NODES / 4, 256, 0, stream>>>(conf16, x16, indptr, deg, esrc, agg16);
        // s = agg@wl + bl + [conf|x]@wr   (K=512 fused; in-place over agg16)
        k_gemm<256, 0><<<gblk, 512, 0, stream>>>(agg16, 256, conf16, 64, x16, 192,
                                                 sB[l], W[7*l+1], nullptr, agg16, nullptr, N_NODES);
        // h = lrelu(s@mw0 + mb0)
        k_gemm<192, 1><<<gblk, 512, 0, stream>>>(agg16, 256, nullptr, 0, nullptr, 0,
                                                 mw0t[l], W[7*l+4], nullptr, node16, nullptr, N_NODES);
        // x = x + lrelu(h@mw1 + mb1)  -> out(f32) + x16
        k_gemm<192, 3><<<gblk, 512, 0, stream>>>(node16, 192, nullptr, 0, nullptr, 0,
                                                 mw1t[l], W[7*l+6], out, x16, out, N_NODES);
    }
}

// Round 2
// 601.429 us; speedup vs baseline: 1.1808x; 1.1808x over previous
//
#include <hip/hip_runtime.h>
#include <stdint.h>

#define N_NODES 100000
#define N_EDGES 800000

typedef unsigned short u16;
typedef __attribute__((ext_vector_type(8))) short bf16x8;
typedef __attribute__((ext_vector_type(8))) unsigned short ushort8;
typedef __attribute__((ext_vector_type(4))) float f32x4;

struct alignas(8) U16x4 { u16 x, y, z, w; };

__device__ __forceinline__ u16 f2b(float f) {
    union { float f; unsigned u; } x; x.f = f;
    unsigned r = (x.u + 0x7FFFu + ((x.u >> 16) & 1u)) >> 16;
    return (u16)r;
}
__device__ __forceinline__ float b2f(u16 h) {
    union { unsigned u; float f; } x; x.u = ((unsigned)h) << 16;
    return x.f;
}

__device__ __forceinline__ void gload_lds16(const void* g, void* l) {
    __builtin_amdgcn_global_load_lds(
        (const __attribute__((address_space(1))) char*)(uintptr_t)g,
        (__attribute__((address_space(3))) char*)(uintptr_t)l,
        16, 0, 0);
}

// ---------------- casts & weight packing ----------------

__global__ void k_cast_bf16(const float* __restrict__ in, u16* __restrict__ out, int n4) {
    int i = blockIdx.x * blockDim.x + threadIdx.x;
    if (i < n4) {
        float4 v = ((const float4*)in)[i];
        U16x4 o; o.x = f2b(v.x); o.y = f2b(v.y); o.z = f2b(v.z); o.w = f2b(v.w);
        ((U16x4*)out)[i] = o;
    }
}

// Pack W^T into MFMA-fragment order:
// idx = (((ks*(Ncol/16) + cb)*4 + k8)*16 + c15)*8 + kq
// content = bf16( src[k][col] ), col = cb*16+c15, k = ks*32 + k8*8 + kq
// so that a wave's b-fragment read is 64 consecutive 16B LDS slots.
__global__ void k_pack_wt(const float* __restrict__ s0, int K0,
                          const float* __restrict__ s1, int K1,
                          int Ncol, u16* __restrict__ dst) {
    int idx = blockIdx.x * blockDim.x + threadIdx.x;
    int Ktot = K0 + K1;
    if (idx >= Ncol * Ktot) return;
    int kq = idx & 7;
    int t = idx >> 3;
    int c15 = t & 15; t >>= 4;
    int k8 = t & 3;  t >>= 2;
    int nb = Ncol >> 4;
    int cb = t % nb;
    int ks = t / nb;
    int col = cb * 16 + c15;
    int k = ks * 32 + k8 * 8 + kq;
    float v = (k < K0) ? s0[(size_t)k * Ncol + col] : s1[(size_t)(k - K0) * Ncol + col];
    dst[idx] = f2b(v);
}

// ---------------- CSR build ----------------

__global__ void k_count(const int* __restrict__ dst, int* __restrict__ deg) {
    int e = blockIdx.x * blockDim.x + threadIdx.x;
    if (e < N_EDGES) atomicAdd(&deg[dst[e]], 1);
}

__global__ void k_scan1(const int* __restrict__ deg, int* __restrict__ excl,
                        int* __restrict__ bsum, int n) {
    __shared__ int sh[512];
    int t = threadIdx.x;
    int base = blockIdx.x * 2048 + t * 4;
    int v0 = (base + 0 < n) ? deg[base + 0] : 0;
    int v1 = (base + 1 < n) ? deg[base + 1] : 0;
    int v2 = (base + 2 < n) ? deg[base + 2] : 0;
    int v3 = (base + 3 < n) ? deg[base + 3] : 0;
    int tot = v0 + v1 + v2 + v3;
    sh[t] = tot;
    __syncthreads();
    for (int off = 1; off < 512; off <<= 1) {
        int x = (t >= off) ? sh[t - off] : 0;
        __syncthreads();
        sh[t] += x;
        __syncthreads();
    }
    int run = sh[t] - tot;
    if (base + 0 < n) excl[base + 0] = run; run += v0;
    if (base + 1 < n) excl[base + 1] = run; run += v1;
    if (base + 2 < n) excl[base + 2] = run; run += v2;
    if (base + 3 < n) excl[base + 3] = run;
    if (t == 511) bsum[blockIdx.x] = sh[t];
}

__global__ void k_scan2(int* __restrict__ bsum, int nb) {
    __shared__ int sh[64];
    int t = threadIdx.x;
    int v = (t < nb) ? bsum[t] : 0;
    sh[t] = v;
    __syncthreads();
    for (int off = 1; off < 64; off <<= 1) {
        int x = (t >= off) ? sh[t - off] : 0;
        __syncthreads();
        sh[t] += x;
        __syncthreads();
    }
    if (t < nb) bsum[t] = sh[t] - v;
}

__global__ void k_scan3(int* __restrict__ excl, const int* __restrict__ bsum,
                        int* __restrict__ cursor, int n) {
    int i = blockIdx.x * blockDim.x + threadIdx.x;
    if (i < n) {
        int v = excl[i] + bsum[i >> 11];
        excl[i] = v;
        cursor[i] = v;
    }
}

__global__ void k_scatter(const int* __restrict__ src, const int* __restrict__ dst,
                          int* __restrict__ cursor, int* __restrict__ esrc) {
    int e = blockIdx.x * blockDim.x + threadIdx.x;
    if (e < N_EDGES) {
        int p = atomicAdd(&cursor[dst[e]], 1);
        esrc[p] = src[e];
    }
}

// ---------------- segment-max aggregation ----------------
// One wave per node; half-wave (32 lanes x 16B) covers one 512B row,
// two edges per iteration + 2x unroll -> 4 row loads in flight.

__global__ __launch_bounds__(256) void k_agg(
    const u16* __restrict__ conf16, const u16* __restrict__ x16,
    const int* __restrict__ indptr, const int* __restrict__ deg,
    const int* __restrict__ esrc, u16* __restrict__ agg) {
    int node = blockIdx.x * 4 + (threadIdx.x >> 6);
    if (node >= N_NODES) return;
    int lane = threadIdx.x & 63;
    int half = lane >> 5;     // which edge of the pair
    int hl = lane & 31;       // 16B chunk index within the 256-dim row
    int start = indptr[node];
    int d = deg[node];
    const bool isConf = hl < 8;
    const u16* bp = isConf ? (conf16 + hl * 8) : (x16 + hl * 8 - 64);
    const int stride = isConf ? 64 : 192;
    float m[8];
    #pragma unroll
    for (int j = 0; j < 8; ++j) m[j] = -1e30f;
    int e = 0;
    for (; e + 4 <= d; e += 4) {
        int sA = esrc[start + e + half];
        int sB = esrc[start + e + 2 + half];
        ushort8 vA = *(const ushort8*)(bp + (size_t)sA * stride);
        ushort8 vB = *(const ushort8*)(bp + (size_t)sB * stride);
        #pragma unroll
        for (int j = 0; j < 8; ++j)
            m[j] = fmaxf(m[j], fmaxf(b2f(vA[j]), b2f(vB[j])));
    }
    for (; e < d; ++e) {   // tail: both halves process the same edge (harmless)
        int s = esrc[start + e];
        ushort8 v = *(const ushort8*)(bp + (size_t)s * stride);
        #pragma unroll
        for (int j = 0; j < 8; ++j)
            m[j] = fmaxf(m[j], b2f(v[j]));
    }
    #pragma unroll
    for (int j = 0; j < 8; ++j)
        m[j] = fmaxf(m[j], __shfl_xor(m[j], 32, 64));
    if (d == 0) {
        #pragma unroll
        for (int j = 0; j < 8; ++j) m[j] = 0.f;
    }
    if (half == 0) {
        ushort8 o;
        #pragma unroll
        for (int j = 0; j < 8; ++j) o[j] = f2b(m[j]);
        *(ushort8*)(agg + (size_t)node * 256 + hl * 8) = o;
    }
}

// ---------------- MFMA GEMM ----------------
// C[nrows, BN] = concat_K(A0|A1|A2) @ Bt^T (+bias, +epilogue)
// Bt is prepacked in fragment order (see k_pack_wt); A is staged via
// global_load_lds with a permuted SOURCE index so the LDS tile lands in
// fragment order too -> every ds_read_b128 is 64 consecutive 16B slots
// (conflict-free), LDS stays linear.
// EPI: 0 = bias -> bf16            (sage linear)
//      1 = bias,lrelu -> bf16      (prenet both, mlp hidden)
//      3 = bf16resid + lrelu(bias+acc) -> bf16   (layer0 mlp final)
//      4 = bf16resid + lrelu(bias+acc) -> f32 d_out (layer1 mlp final)

template<int BN, int EPI>
__global__ __launch_bounds__(512, 2) void k_gemm(
    const u16* __restrict__ A0, int K0,
    const u16* __restrict__ A1, int K1,
    const u16* __restrict__ A2, int K2,
    const u16* __restrict__ Bt,
    const float* __restrict__ bias,
    float* __restrict__ outf,
    u16* __restrict__ outb,
    const u16* __restrict__ resid16,
    int nrows)
{
    constexpr int FN = BN / 64;           // b-frags per wave (4 or 3)
    constexpr int ASZ = 128 * 32;         // A tile elems
    constexpr int BSLOTS = BN * 4;        // 16B slots in B tile
    __shared__ u16 lds[2][ASZ + BN * 32] __attribute__((aligned(16)));

    const int tid = threadIdx.x;
    const int wave = tid >> 6;
    const int lane = tid & 63;
    const int wr = wave >> 2;             // 0..1
    const int wc = wave & 3;              // 0..3
    const int rowbase = blockIdx.x * 128;
    const int Ktot = K0 + K1 + K2;
    const int nk = Ktot >> 5;

    f32x4 zero = {0.f, 0.f, 0.f, 0.f};
    f32x4 acc[4][FN];
    #pragma unroll
    for (int fm = 0; fm < 4; ++fm)
        #pragma unroll
        for (int fn = 0; fn < FN; ++fn)
            acc[fm][fn] = zero;

    auto stage = [&](int buf, int ks) {
        const int k0 = ks * 32;
        const u16* segp; int segoff, segK;
        if (k0 < K0)           { segp = A0; segoff = k0;           segK = K0; }
        else if (k0 < K0 + K1) { segp = A1; segoff = k0 - K0;      segK = K1; }
        else                   { segp = A2; segoff = k0 - K0 - K1; segK = K2; }
        {   // A tile in fragment order: slot tid -> row = wave*16 + (tid&15),
            // k8 = (tid>>4)&3 ; LDS dest linear (wave-uniform base + lane*16)
            int row = ((tid >> 6) << 4) | (tid & 15);
            int grow = rowbase + row;
            if (grow >= nrows) grow = nrows - 1;
            const u16* g = segp + (size_t)grow * segK + segoff + ((tid >> 4) & 3) * 8;
            gload_lds16(g, &lds[buf][wave * 512]);
        }
        #pragma unroll
        for (int it = 0; it < (BSLOTS + 511) / 512; ++it) {
            int slot = it * 512 + tid;
            if (slot < BSLOTS) {          // wave-uniform predicate
                const u16* g = Bt + (size_t)ks * BN * 32 + slot * 8;
                gload_lds16(g, &lds[buf][ASZ + it * 4096 + wave * 512]);
            }
        }
    };

    stage(0, 0);
    __syncthreads();

    const int l15 = lane & 15, l4 = lane >> 4;

    for (int ks = 0; ks < nk; ++ks) {
        const int cur = ks & 1;
        if (ks + 1 < nk) stage(cur ^ 1, ks + 1);
        const u16* la = &lds[cur][0];
        const u16* lb = &lds[cur][ASZ];
        bf16x8 a[4], b[FN];
        #pragma unroll
        for (int fm = 0; fm < 4; ++fm)
            a[fm] = *(const bf16x8*)(la + (wr * 4 + fm) * 512 + lane * 8);
        #pragma unroll
        for (int fn = 0; fn < FN; ++fn)
            b[fn] = *(const bf16x8*)(lb + (wc * FN + fn) * 512 + lane * 8);
        #pragma unroll
        for (int fm = 0; fm < 4; ++fm)
            #pragma unroll
            for (int fn = 0; fn < FN; ++fn)
                acc[fm][fn] = __builtin_amdgcn_mfma_f32_16x16x32_bf16(a[fm], b[fn], acc[fm][fn], 0, 0, 0);
        __syncthreads();
    }

    // epilogue: C/D layout col = lane&15, row = (lane>>4)*4 + r
    const int r0 = rowbase + wr * 64;
    const int c0 = wc * (FN * 16);
    #pragma unroll
    for (int fn = 0; fn < FN; ++fn) {
        const int col = c0 + fn * 16 + l15;
        const float bs = bias[col];
        #pragma unroll
        for (int fm = 0; fm < 4; ++fm) {
            #pragma unroll
            for (int r = 0; r < 4; ++r) {
                const int row = r0 + fm * 16 + l4 * 4 + r;
                if (row < nrows) {
                    float v = acc[fm][fn][r] + bs;
                    if (EPI >= 1) v = (v >= 0.f) ? v : 0.2f * v;
                    if (EPI == 3 || EPI == 4) v += b2f(resid16[(size_t)row * BN + col]);
                    if (EPI == 4) outf[(size_t)row * BN + col] = v;
                    else          outb[(size_t)row * BN + col] = f2b(v);
                }
            }
        }
    }
}

// ---------------- host ----------------

extern "C" void kernel_launch(void* const* d_in, const int* in_sizes, int n_in,
                              void* d_out, int out_size, void* d_ws, size_t ws_size,
                              hipStream_t stream)
{
    (void)in_sizes; (void)n_in; (void)out_size; (void)ws_size;
    const float* node = (const float*)d_in[0];
    const float* conf = (const float*)d_in[1];
    const int* edges  = (const int*)d_in[2];
    const float* pw0  = (const float*)d_in[3];
    const float* pb0  = (const float*)d_in[4];
    const float* pw1  = (const float*)d_in[5];
    const float* pb1  = (const float*)d_in[6];
    const float* W[14];
    for (int i = 0; i < 14; ++i) W[i] = (const float*)d_in[7 + i];
    float* out = (float*)d_out;
    const int* e_src = edges;
    const int* e_dst = edges + N_EDGES;

    char* w = (char*)d_ws;
    auto alloc = [&](size_t b) { char* p = w; w += (b + 255) & ~(size_t)255; return p; };
    u16* conf16 = (u16*)alloc((size_t)N_NODES * 64 * 2);
    u16* node16 = (u16*)alloc((size_t)N_NODES * 192 * 2);   // prenet input, later h
    u16* x16    = (u16*)alloc((size_t)N_NODES * 192 * 2);   // bf16 residual stream
    u16* agg16  = (u16*)alloc((size_t)N_NODES * 256 * 2);   // agg, then s (in-place)
    int* deg    = (int*)alloc((size_t)N_NODES * 4);
    int* indptr = (int*)alloc((size_t)N_NODES * 4);
    int* cursor = (int*)alloc((size_t)N_NODES * 4);
    int* esrc   = (int*)alloc((size_t)N_EDGES * 4);
    int* bsum   = (int*)alloc(4096);
    u16* pw0t   = (u16*)alloc((size_t)192 * 256 * 2);
    u16* pw1t   = (u16*)alloc((size_t)192 * 192 * 2);
    u16 *sB[2], *mw0t[2], *mw1t[2];
    for (int l = 0; l < 2; ++l) {
        sB[l]   = (u16*)alloc((size_t)256 * 512 * 2);
        mw0t[l] = (u16*)alloc((size_t)192 * 256 * 2);
        mw1t[l] = (u16*)alloc((size_t)192 * 192 * 2);
    }

    // input casts
    k_cast_bf16<<<(N_NODES * 64 / 4 + 255) / 256, 256, 0, stream>>>(conf, conf16, N_NODES * 64 / 4);
    k_cast_bf16<<<(N_NODES * 192 / 4 + 255) / 256, 256, 0, stream>>>(node, node16, N_NODES * 192 / 4);
    // weight packs (fragment-order bf16)
    k_pack_wt<<<(192 * 256 + 255) / 256, 256, 0, stream>>>(pw0, 256, nullptr, 0, 192, pw0t);
    k_pack_wt<<<(192 * 192 + 255) / 256, 256, 0, stream>>>(pw1, 192, nullptr, 0, 192, pw1t);
    for (int l = 0; l < 2; ++l) {
        k_pack_wt<<<(256 * 512 + 255) / 256, 256, 0, stream>>>(W[7*l+0], 256, W[7*l+2], 256, 256, sB[l]);
        k_pack_wt<<<(192 * 256 + 255) / 256, 256, 0, stream>>>(W[7*l+3], 256, nullptr, 0, 192, mw0t[l]);
        k_pack_wt<<<(192 * 192 + 255) / 256, 256, 0, stream>>>(W[7*l+5], 192, nullptr, 0, 192, mw1t[l]);
    }
    // CSR (edges constant per launch)
    (void)hipMemsetAsync(deg, 0, (size_t)N_NODES * 4, stream);
    k_count<<<(N_EDGES + 255) / 256, 256, 0, stream>>>(e_dst, deg);
    int nb = (N_NODES + 2047) / 2048;
    k_scan1<<<nb, 512, 0, stream>>>(deg, indptr, bsum, N_NODES);
    k_scan2<<<1, 64, 0, stream>>>(bsum, nb);
    k_scan3<<<(N_NODES + 255) / 256, 256, 0, stream>>>(indptr, bsum, cursor, N_NODES);
    k_scatter<<<(N_EDGES + 255) / 256, 256, 0, stream>>>(e_src, e_dst, cursor, esrc);

    const int gblk = (N_NODES + 127) / 128;   // 782
    // prenet: x16 = lrelu(lrelu([conf|node]@w0+b0)@w1 + b1)
    k_gemm<192, 1><<<gblk, 512, 0, stream>>>(conf16, 64, node16, 192, nullptr, 0,
                                             pw0t, pb0, nullptr, x16, nullptr, N_NODES);
    k_gemm<192, 1><<<gblk, 512, 0, stream>>>(x16, 192, nullptr, 0, nullptr, 0,
                                             pw1t, pb1, nullptr, x16, nullptr, N_NODES);
    for (int l = 0; l < 2; ++l) {
        k_agg<<<N_NODES / 4, 256, 0, stream>>>(conf16, x16, indptr, deg, esrc, agg16);
        // s = agg@wl + bl + [conf|x]@wr   (K=512 fused; in-place over agg16)
        k_gemm<256, 0><<<gblk, 512, 0, stream>>>(agg16, 256, conf16, 64, x16, 192,
                                                 sB[l], W[7*l+1], nullptr, agg16, nullptr, N_NODES);
        // h = lrelu(s@mw0 + mb0)
        k_gemm<192, 1><<<gblk, 512, 0, stream>>>(agg16, 256, nullptr, 0, nullptr, 0,
                                                 mw0t[l], W[7*l+4], nullptr, node16, nullptr, N_NODES);
        // x = x + lrelu(h@mw1 + mb1)  (layer1 also writes f32 d_out)
        if (l == 0)
            k_gemm<192, 3><<<gblk, 512, 0, stream>>>(node16, 192, nullptr, 0, nullptr, 0,
                                                     mw1t[l], W[7*l+6], nullptr, x16, x16, N_NODES);
        else
            k_gemm<192, 4><<<gblk, 512, 0, stream>>>(node16, 192, nullptr, 0, nullptr, 0,
                                                     mw1t[l], W[7*l+6], out, nullptr, x16, N_NODES);
    }
}

// Round 3
// 584.151 us; speedup vs baseline: 1.2157x; 1.0296x over previous
//
#include <hip/hip_runtime.h>
#include <stdint.h>

#define N_NODES 100000
#define N_EDGES 800000

typedef unsigned short u16;
typedef __attribute__((ext_vector_type(8))) short bf16x8;
typedef __attribute__((ext_vector_type(8))) unsigned short ushort8;
typedef __attribute__((ext_vector_type(4))) float f32x4;
typedef __attribute__((ext_vector_type(4))) int i32x4;

struct alignas(8) U16x4 { u16 x, y, z, w; };

__device__ __forceinline__ u16 f2b(float f) {
    union { float f; unsigned u; } x; x.f = f;
    unsigned r = (x.u + 0x7FFFu + ((x.u >> 16) & 1u)) >> 16;
    return (u16)r;
}
__device__ __forceinline__ float b2f(u16 h) {
    union { unsigned u; float f; } x; x.u = ((unsigned)h) << 16;
    return x.f;
}

__device__ __forceinline__ void gload_lds16(const void* g, void* l) {
    __builtin_amdgcn_global_load_lds(
        (const __attribute__((address_space(1))) char*)(uintptr_t)g,
        (__attribute__((address_space(3))) char*)(uintptr_t)l,
        16, 0, 0);
}

// ---------------- fused input cast + deg zeroing ----------------

__global__ void k_prep(const float* __restrict__ conf, const float* __restrict__ node,
                       u16* __restrict__ conf16, u16* __restrict__ node16,
                       int* __restrict__ deg) {
    const int c4 = N_NODES * 64 / 4;
    const int n4 = N_NODES * 192 / 4;
    int i = blockIdx.x * blockDim.x + threadIdx.x;
    if (i < c4) {
        float4 v = ((const float4*)conf)[i];
        U16x4 o; o.x = f2b(v.x); o.y = f2b(v.y); o.z = f2b(v.z); o.w = f2b(v.w);
        ((U16x4*)conf16)[i] = o;
    } else if (i < c4 + n4) {
        float4 v = ((const float4*)node)[i - c4];
        U16x4 o; o.x = f2b(v.x); o.y = f2b(v.y); o.z = f2b(v.z); o.w = f2b(v.w);
        ((U16x4*)node16)[i - c4] = o;
    } else if (i < c4 + n4 + N_NODES / 4) {
        i32x4 z = {0, 0, 0, 0};
        ((i32x4*)deg)[i - c4 - n4] = z;
    }
}

// ---------------- fused weight packing (fragment order) ----------------
// dst[li]: li = (((ks*(Ncol/16)+cb)*4+k8)*16+c15)*8+kq
// value = bf16(src[k][col]), col=cb*16+c15, k=ks*32+k8*8+kq; src = a (k<K0) else b.

struct PackSeg { const float* a; const float* b; u16* dst; int K0, K1, Ncol, beg, end; };
struct PackArgs { PackSeg s[8]; };

__global__ void k_pack(PackArgs p, int total) {
    int idx = blockIdx.x * blockDim.x + threadIdx.x;
    if (idx >= total) return;
    #pragma unroll
    for (int si = 0; si < 8; ++si) {
        if (idx >= p.s[si].beg && idx < p.s[si].end) {
            int li = idx - p.s[si].beg;
            int Ncol = p.s[si].Ncol, K0 = p.s[si].K0;
            int kq = li & 7;
            int t = li >> 3;
            int c15 = t & 15; t >>= 4;
            int k8 = t & 3;  t >>= 2;
            int nb = Ncol >> 4;
            int cb = t % nb;
            int ks = t / nb;
            int col = cb * 16 + c15;
            int k = ks * 32 + k8 * 8 + kq;
            float v = (k < K0) ? p.s[si].a[(size_t)k * Ncol + col]
                               : p.s[si].b[(size_t)(k - K0) * Ncol + col];
            p.s[si].dst[li] = f2b(v);
        }
    }
}

// ---------------- CSR build ----------------

__global__ void k_count(const int* __restrict__ dst, int* __restrict__ deg) {
    int e = blockIdx.x * blockDim.x + threadIdx.x;
    if (e < N_EDGES) atomicAdd(&deg[dst[e]], 1);
}

__global__ void k_scan1(const int* __restrict__ deg, int* __restrict__ excl,
                        int* __restrict__ bsum, int n) {
    __shared__ int sh[512];
    int t = threadIdx.x;
    int base = blockIdx.x * 2048 + t * 4;
    int v0 = (base + 0 < n) ? deg[base + 0] : 0;
    int v1 = (base + 1 < n) ? deg[base + 1] : 0;
    int v2 = (base + 2 < n) ? deg[base + 2] : 0;
    int v3 = (base + 3 < n) ? deg[base + 3] : 0;
    int tot = v0 + v1 + v2 + v3;
    sh[t] = tot;
    __syncthreads();
    for (int off = 1; off < 512; off <<= 1) {
        int x = (t >= off) ? sh[t - off] : 0;
        __syncthreads();
        sh[t] += x;
        __syncthreads();
    }
    int run = sh[t] - tot;
    if (base + 0 < n) excl[base + 0] = run; run += v0;
    if (base + 1 < n) excl[base + 1] = run; run += v1;
    if (base + 2 < n) excl[base + 2] = run; run += v2;
    if (base + 3 < n) excl[base + 3] = run;
    if (t == 511) bsum[blockIdx.x] = sh[t];
}

__global__ void k_scan2(int* __restrict__ bsum, int nb) {
    __shared__ int sh[64];
    int t = threadIdx.x;
    int v = (t < nb) ? bsum[t] : 0;
    sh[t] = v;
    __syncthreads();
    for (int off = 1; off < 64; off <<= 1) {
        int x = (t >= off) ? sh[t - off] : 0;
        __syncthreads();
        sh[t] += x;
        __syncthreads();
    }
    if (t < nb) bsum[t] = sh[t] - v;
}

__global__ void k_scan3(int* __restrict__ excl, const int* __restrict__ bsum,
                        int* __restrict__ cursor, int n) {
    int i = blockIdx.x * blockDim.x + threadIdx.x;
    if (i < n) {
        int v = excl[i] + bsum[i >> 11];
        excl[i] = v;
        cursor[i] = v;
    }
}

__global__ void k_scatter(const int* __restrict__ src, const int* __restrict__ dst,
                          int* __restrict__ cursor, int* __restrict__ esrc) {
    int e = blockIdx.x * blockDim.x + threadIdx.x;
    if (e < N_EDGES) {
        int p = atomicAdd(&cursor[dst[e]], 1);
        esrc[p] = src[e];
    }
}

// ---------------- segment-max aggregation ----------------
// One wave per node, 4 nodes/block. Edge lists of the block's 4 nodes are
// contiguous in CSR -> staged into LDS (cap 512, uniform fallback).
// CHUNKS=32: full [conf|x] row (512B), 2 edges across wave halves; saves
//            conf-part max to aggC.
// CHUNKS=24: x-part only (384B), 2 edges across lanes 0-23 / 24-47; lanes
//            48-55 copy aggC into the output row.
// All rounds are full 8-edge unrolls with indices clamped to d-1 (dup-safe
// for max) -> no serial tail; 4 independent 16B loads per lane per round.

template<int CHUNKS>
__global__ __launch_bounds__(256) void k_agg(
    const u16* __restrict__ conf16, const u16* __restrict__ x16,
    const int* __restrict__ indptr, const int* __restrict__ deg,
    const int* __restrict__ iend, const int* __restrict__ esrc,
    u16* __restrict__ agg, u16* __restrict__ aggC) {
    __shared__ int se[512];
    __shared__ int sinfo[2];
    const int b4 = blockIdx.x * 4;
    if (threadIdx.x == 0) {
        sinfo[0] = indptr[b4];
        sinfo[1] = iend[b4 + 3];
    }
    __syncthreads();
    const int sbase = sinfo[0];
    const int slen = sinfo[1] - sbase;
    const bool useLds = slen <= 512;
    if (useLds) {
        for (int i = threadIdx.x; i < slen; i += 256) se[i] = esrc[sbase + i];
    }
    __syncthreads();

    const int node = b4 + (threadIdx.x >> 6);
    const int lane = threadIdx.x & 63;
    constexpr int ACTIVE = (CHUNKS == 32) ? 64 : 48;
    const int e_sub = (CHUNKS == 32) ? (lane >> 5) : (lane >= 24 ? 1 : 0);
    const int ch = lane - e_sub * CHUNKS;
    const int start = indptr[node];
    const int d = deg[node];

    const u16* bp;
    int stride;
    if (CHUNKS == 32) {
        const bool isConf = ch < 8;
        bp = isConf ? (conf16 + ch * 8) : (x16 + ch * 8 - 64);
        stride = isConf ? 64 : 192;
    } else {
        bp = x16 + (ch < 24 ? ch : 0) * 8;
        stride = 192;
    }

    float m[8];
    #pragma unroll
    for (int j = 0; j < 8; ++j) m[j] = -1e30f;

    if (lane < ACTIVE && d > 0) {
        const int rounds = (d + 7) >> 3;
        const int lbase = start - sbase;
        for (int rr = 0; rr < rounds; ++rr) {
            const int b0 = rr * 8 + e_sub;
            const int dm1 = d - 1;
            int i0 = min(b0, dm1), i1 = min(b0 + 2, dm1);
            int i2 = min(b0 + 4, dm1), i3 = min(b0 + 6, dm1);
            int s0, s1, s2, s3;
            if (useLds) {
                s0 = se[lbase + i0]; s1 = se[lbase + i1];
                s2 = se[lbase + i2]; s3 = se[lbase + i3];
            } else {
                s0 = esrc[start + i0]; s1 = esrc[start + i1];
                s2 = esrc[start + i2]; s3 = esrc[start + i3];
            }
            ushort8 v0 = *(const ushort8*)(bp + (size_t)s0 * stride);
            ushort8 v1 = *(const ushort8*)(bp + (size_t)s1 * stride);
            ushort8 v2 = *(const ushort8*)(bp + (size_t)s2 * stride);
            ushort8 v3 = *(const ushort8*)(bp + (size_t)s3 * stride);
            #pragma unroll
            for (int j = 0; j < 8; ++j) {
                float a = fmaxf(b2f(v0[j]), b2f(v1[j]));
                float b = fmaxf(b2f(v2[j]), b2f(v3[j]));
                m[j] = fmaxf(m[j], fmaxf(a, b));
            }
        }
    }

    // combine the two edge-subsets
    if (CHUNKS == 32) {
        #pragma unroll
        for (int j = 0; j < 8; ++j)
            m[j] = fmaxf(m[j], __shfl_xor(m[j], 32, 64));
    } else {
        #pragma unroll
        for (int j = 0; j < 8; ++j)
            m[j] = fmaxf(m[j], __shfl(m[j], lane + 24, 64));
    }
    if (d == 0) {
        #pragma unroll
        for (int j = 0; j < 8; ++j) m[j] = 0.f;
    }

    if (CHUNKS == 32) {
        if (lane < 32) {
            ushort8 o;
            #pragma unroll
            for (int j = 0; j < 8; ++j) o[j] = f2b(m[j]);
            *(ushort8*)(agg + (size_t)node * 256 + lane * 8) = o;
            if (lane < 8)
                *(ushort8*)(aggC + (size_t)node * 64 + lane * 8) = o;
        }
    } else {
        if (lane < 24) {
            ushort8 o;
            #pragma unroll
            for (int j = 0; j < 8; ++j) o[j] = f2b(m[j]);
            *(ushort8*)(agg + (size_t)node * 256 + 64 + lane * 8) = o;
        } else if (lane >= 48 && lane < 56) {
            const int c2 = lane - 48;
            ushort8 v = *(const ushort8*)(aggC + (size_t)node * 64 + c2 * 8);
            *(ushort8*)(agg + (size_t)node * 256 + c2 * 8) = v;
        }
    }
}

// ---------------- MFMA GEMM ----------------
// C[nrows, BN] = concat_K(A0|A1|A2) @ Bt^T (+bias, +epilogue)
// Bt prepacked in fragment order; A staged via global_load_lds with permuted
// SOURCE index so LDS lands in fragment order -> conflict-free ds_read_b128.
// EPI: 0 = bias -> bf16            (sage linear)
//      1 = bias,lrelu -> bf16      (prenet both, mlp hidden)
//      3 = bf16resid + lrelu(bias+acc) -> bf16   (layer0 mlp final)
//      4 = bf16resid + lrelu(bias+acc) -> f32 d_out (layer1 mlp final)

template<int BN, int EPI>
__global__ __launch_bounds__(512, 2) void k_gemm(
    const u16* __restrict__ A0, int K0,
    const u16* __restrict__ A1, int K1,
    const u16* __restrict__ A2, int K2,
    const u16* __restrict__ Bt,
    const float* __restrict__ bias,
    float* __restrict__ outf,
    u16* __restrict__ outb,
    const u16* __restrict__ resid16,
    int nrows)
{
    constexpr int FN = BN / 64;           // b-frags per wave (4 or 3)
    constexpr int ASZ = 128 * 32;         // A tile elems
    constexpr int BSLOTS = BN * 4;        // 16B slots in B tile
    __shared__ u16 lds[2][ASZ + BN * 32] __attribute__((aligned(16)));

    const int tid = threadIdx.x;
    const int wave = tid >> 6;
    const int lane = tid & 63;
    const int wr = wave >> 2;             // 0..1
    const int wc = wave & 3;              // 0..3
    const int rowbase = blockIdx.x * 128;
    const int Ktot = K0 + K1 + K2;
    const int nk = Ktot >> 5;

    f32x4 zero = {0.f, 0.f, 0.f, 0.f};
    f32x4 acc[4][FN];
    #pragma unroll
    for (int fm = 0; fm < 4; ++fm)
        #pragma unroll
        for (int fn = 0; fn < FN; ++fn)
            acc[fm][fn] = zero;

    auto stage = [&](int buf, int ks) {
        const int k0 = ks * 32;
        const u16* segp; int segoff, segK;
        if (k0 < K0)           { segp = A0; segoff = k0;           segK = K0; }
        else if (k0 < K0 + K1) { segp = A1; segoff = k0 - K0;      segK = K1; }
        else                   { segp = A2; segoff = k0 - K0 - K1; segK = K2; }
        {   // A tile in fragment order: slot tid -> row = wave*16 + (tid&15),
            // k8 = (tid>>4)&3 ; LDS dest linear (wave-uniform base + lane*16)
            int row = ((tid >> 6) << 4) | (tid & 15);
            int grow = rowbase + row;
            if (grow >= nrows) grow = nrows - 1;
            const u16* g = segp + (size_t)grow * segK + segoff + ((tid >> 4) & 3) * 8;
            gload_lds16(g, &lds[buf][wave * 512]);
        }
        #pragma unroll
        for (int it = 0; it < (BSLOTS + 511) / 512; ++it) {
            int slot = it * 512 + tid;
            if (slot < BSLOTS) {          // wave-uniform predicate
                const u16* g = Bt + (size_t)ks * BN * 32 + slot * 8;
                gload_lds16(g, &lds[buf][ASZ + it * 4096 + wave * 512]);
            }
        }
    };

    stage(0, 0);
    __syncthreads();

    const int l15 = lane & 15, l4 = lane >> 4;

    for (int ks = 0; ks < nk; ++ks) {
        const int cur = ks & 1;
        if (ks + 1 < nk) stage(cur ^ 1, ks + 1);
        const u16* la = &lds[cur][0];
        const u16* lb = &lds[cur][ASZ];
        bf16x8 a[4], b[FN];
        #pragma unroll
        for (int fm = 0; fm < 4; ++fm)
            a[fm] = *(const bf16x8*)(la + (wr * 4 + fm) * 512 + lane * 8);
        #pragma unroll
        for (int fn = 0; fn < FN; ++fn)
            b[fn] = *(const bf16x8*)(lb + (wc * FN + fn) * 512 + lane * 8);
        #pragma unroll
        for (int fm = 0; fm < 4; ++fm)
            #pragma unroll
            for (int fn = 0; fn < FN; ++fn)
                acc[fm][fn] = __builtin_amdgcn_mfma_f32_16x16x32_bf16(a[fm], b[fn], acc[fm][fn], 0, 0, 0);
        __syncthreads();
    }

    // epilogue: C/D layout col = lane&15, row = (lane>>4)*4 + r
    const int r0 = rowbase + wr * 64;
    const int c0 = wc * (FN * 16);
    #pragma unroll
    for (int fn = 0; fn < FN; ++fn) {
        const int col = c0 + fn * 16 + l15;
        const float bs = bias[col];
        #pragma unroll
        for (int fm = 0; fm < 4; ++fm) {
            #pragma unroll
            for (int r = 0; r < 4; ++r) {
                const int row = r0 + fm * 16 + l4 * 4 + r;
                if (row < nrows) {
                    float v = acc[fm][fn][r] + bs;
                    if (EPI >= 1) v = (v >= 0.f) ? v : 0.2f * v;
                    if (EPI == 3 || EPI == 4) v += b2f(resid16[(size_t)row * BN + col]);
                    if (EPI == 4) outf[(size_t)row * BN + col] = v;
                    else          outb[(size_t)row * BN + col] = f2b(v);
                }
            }
        }
    }
}

// ---------------- host ----------------

extern "C" void kernel_launch(void* const* d_in, const int* in_sizes, int n_in,
                              void* d_out, int out_size, void* d_ws, size_t ws_size,
                              hipStream_t stream)
{
    (void)in_sizes; (void)n_in; (void)out_size; (void)ws_size;
    const float* node = (const float*)d_in[0];
    const float* conf = (const float*)d_in[1];
    const int* edges  = (const int*)d_in[2];
    const float* pw0  = (const float*)d_in[3];
    const float* pb0  = (const float*)d_in[4];
    const float* pw1  = (const float*)d_in[5];
    const float* pb1  = (const float*)d_in[6];
    const float* W[14];
    for (int i = 0; i < 14; ++i) W[i] = (const float*)d_in[7 + i];
    float* out = (float*)d_out;
    const int* e_src = edges;
    const int* e_dst = edges + N_EDGES;

    char* w = (char*)d_ws;
    auto alloc = [&](size_t b) { char* p = w; w += (b + 255) & ~(size_t)255; return p; };
    u16* conf16 = (u16*)alloc((size_t)N_NODES * 64 * 2);
    u16* node16 = (u16*)alloc((size_t)N_NODES * 192 * 2);   // prenet input, later h
    u16* x16    = (u16*)alloc((size_t)N_NODES * 192 * 2);   // bf16 residual stream
    u16* agg16  = (u16*)alloc((size_t)N_NODES * 256 * 2);   // agg, then s (in-place)
    u16* aggC   = (u16*)alloc((size_t)N_NODES * 64 * 2);    // saved conf-part max
    int* deg    = (int*)alloc((size_t)N_NODES * 4);
    int* indptr = (int*)alloc((size_t)N_NODES * 4);
    int* cursor = (int*)alloc((size_t)N_NODES * 4);         // becomes end-ptrs
    int* esrc   = (int*)alloc((size_t)N_EDGES * 4);
    int* bsum   = (int*)alloc(4096);
    u16* pw0t   = (u16*)alloc((size_t)192 * 256 * 2);
    u16* pw1t   = (u16*)alloc((size_t)192 * 192 * 2);
    u16 *sB[2], *mw0t[2], *mw1t[2];
    for (int l = 0; l < 2; ++l) {
        sB[l]   = (u16*)alloc((size_t)256 * 512 * 2);
        mw0t[l] = (u16*)alloc((size_t)192 * 256 * 2);
        mw1t[l] = (u16*)alloc((size_t)192 * 192 * 2);
    }

    // fused cast + deg zero
    {
        const int tot = N_NODES * 64 / 4 + N_NODES * 192 / 4 + N_NODES / 4;
        k_prep<<<(tot + 255) / 256, 256, 0, stream>>>(conf, node, conf16, node16, deg);
    }
    // fused weight packs (fragment order)
    {
        PackArgs pa;
        int off = 0;
        auto seg = [&](int i, const float* a, int K0, const float* b, int K1, int Ncol, u16* dst) {
            int sz = Ncol * (K0 + K1);
            pa.s[i] = {a, b, dst, K0, K1, Ncol, off, off + sz};
            off += sz;
        };
        seg(0, pw0, 256, nullptr, 0, 192, pw0t);
        seg(1, pw1, 192, nullptr, 0, 192, pw1t);
        seg(2, W[0], 256, W[2], 256, 256, sB[0]);
        seg(3, W[3], 256, nullptr, 0, 192, mw0t[0]);
        seg(4, W[5], 192, nullptr, 0, 192, mw1t[0]);
        seg(5, W[7], 256, W[9], 256, 256, sB[1]);
        seg(6, W[10], 256, nullptr, 0, 192, mw0t[1]);
        seg(7, W[12], 192, nullptr, 0, 192, mw1t[1]);
        k_pack<<<(off + 255) / 256, 256, 0, stream>>>(pa, off);
    }
    // CSR
    k_count<<<(N_EDGES + 255) / 256, 256, 0, stream>>>(e_dst, deg);
    int nb = (N_NODES + 2047) / 2048;
    k_scan1<<<nb, 512, 0, stream>>>(deg, indptr, bsum, N_NODES);
    k_scan2<<<1, 64, 0, stream>>>(bsum, nb);
    k_scan3<<<(N_NODES + 255) / 256, 256, 0, stream>>>(indptr, bsum, cursor, N_NODES);
    k_scatter<<<(N_EDGES + 255) / 256, 256, 0, stream>>>(e_src, e_dst, cursor, esrc);
    // cursor now holds per-node END pointers (indptr + deg)

    const int gblk = (N_NODES + 127) / 128;   // 782
    // prenet: x16 = lrelu(lrelu([conf|node]@w0+b0)@w1 + b1)
    k_gemm<192, 1><<<gblk, 512, 0, stream>>>(conf16, 64, node16, 192, nullptr, 0,
                                             pw0t, pb0, nullptr, x16, nullptr, N_NODES);
    k_gemm<192, 1><<<gblk, 512, 0, stream>>>(x16, 192, nullptr, 0, nullptr, 0,
                                             pw1t, pb1, nullptr, x16, nullptr, N_NODES);
    for (int l = 0; l < 2; ++l) {
        if (l == 0)
            k_agg<32><<<N_NODES / 4, 256, 0, stream>>>(conf16, x16, indptr, deg, cursor, esrc, agg16, aggC);
        else
            k_agg<24><<<N_NODES / 4, 256, 0, stream>>>(conf16, x16, indptr, deg, cursor, esrc, agg16, aggC);
        // s = agg@wl + bl + [conf|x]@wr   (K=512 fused; in-place over agg16)
        k_gemm<256, 0><<<gblk, 512, 0, stream>>>(agg16, 256, conf16, 64, x16, 192,
                                                 sB[l], W[7*l+1], nullptr, agg16, nullptr, N_NODES);
        // h = lrelu(s@mw0 + mb0)
        k_gemm<192, 1><<<gblk, 512, 0, stream>>>(agg16, 256, nullptr, 0, nullptr, 0,
                                                 mw0t[l], W[7*l+4], nullptr, node16, nullptr, N_NODES);
        // x = x + lrelu(h@mw1 + mb1)  (layer1 also writes f32 d_out)
        if (l == 0)
            k_gemm<192, 3><<<gblk, 512, 0, stream>>>(node16, 192, nullptr, 0, nullptr, 0,
                                                     mw1t[l], W[7*l+6], nullptr, x16, x16, N_NODES);
        else
            k_gemm<192, 4><<<gblk, 512, 0, stream>>>(node16, 192, nullptr, 0, nullptr, 0,
                                                     mw1t[l], W[7*l+6], out, nullptr, x16, N_NODES);
    }
}